// Round 10
// baseline (238.855 us; speedup 1.0000x reference)
//
#include <hip/hip_runtime.h>
#include <hip/hip_fp16.h>
#include <math.h>

#define NN 10000
#define EE 160000
#define HID 128
constexpr int N128 = NN * HID;
constexpr int PSTR = 384;  // pack stride in halves: [h0 h1 h2]

typedef _Float16 f16;
typedef f16 half8 __attribute__((ext_vector_type(8)));
typedef f16 f16x2 __attribute__((ext_vector_type(2)));
typedef float f32x4 __attribute__((ext_vector_type(4)));

#if __has_builtin(__builtin_amdgcn_fdot2)
__device__ inline float fdot2(f16x2 a, f16x2 b, float c) { return __builtin_amdgcn_fdot2(a, b, c, false); }
#else
__device__ inline float fdot2(f16x2 a, f16x2 b, float c) {
    return fmaf((float)a[0], (float)b[0], fmaf((float)a[1], (float)b[1], c));
}
#endif

// ---------------- degree count (by dst) ----------------
__global__ __launch_bounds__(256) void cnt_count(const int* __restrict__ dst, int* __restrict__ cnt) {
    int e = blockIdx.x * 256 + threadIdx.x;
    if (e < EE) atomicAdd(&cnt[dst[e]], 1);
}

// ---------------- single-block exclusive scan -> rowptr, + dinv fused ----------------
__global__ __launch_bounds__(256) void scan_rowptr(const int* __restrict__ cnt, int* __restrict__ rowptr,
                                                   float* __restrict__ dinv) {
    __shared__ int part[256];
    const int PER = (NN + 255) / 256;  // 40
    int t = threadIdx.x;
    int base = t * PER;
    int sum = 0;
    for (int i = 0; i < PER; ++i) {
        int idx = base + i;
        if (idx < NN) {
            int c = cnt[idx];
            sum += c;
            dinv[idx] = rsqrtf((float)c + 1.0f);  // +1 self-loop
        }
    }
    part[t] = sum;
    __syncthreads();
    for (int ofs = 1; ofs < 256; ofs <<= 1) {
        int v = (t >= ofs) ? part[t - ofs] : 0;
        __syncthreads();
        part[t] += v;
        __syncthreads();
    }
    int run = (t > 0) ? part[t - 1] : 0;
    for (int i = 0; i < PER; ++i) {
        int idx = base + i;
        if (idx <= NN) rowptr[idx] = run;
        if (idx < NN) run += cnt[idx];
    }
}

__global__ __launch_bounds__(256) void scatter_edges(const int* __restrict__ ei,
                                                     const int* __restrict__ rowptr,
                                                     int* __restrict__ fill,
                                                     int* __restrict__ esorted) {
    int e = blockIdx.x * 256 + threadIdx.x;
    if (e < EE) {
        int s = ei[e], d = ei[EE + e];
        int pos = rowptr[d] + atomicAdd(&fill[d], 1);
        esorted[pos] = s;
    }
}

// ---------------- fused prep ----------------
// blocks 0..4: transpose {W1, Wv0, Wv1, Wv2, W2} -> Wt[oc][k] fp16
// blocks 5..20: Wqk fold: idx=b-5, l=1+idx/8, h=idx%8:
//   Wqkt[idx][j*128+i] = sum_{c<16} Wq[l][i][16h+c]*Wk[l][j][16h+c];  bqk[idx][j] = sum_c bq[l][16h+c]*Wk[l][j][16h+c]
// blocks 21..52: zero cnt/fill (128KB)
__global__ __launch_bounds__(256) void prep_fused(
    const float* __restrict__ W1, const float* __restrict__ Wq, const float* __restrict__ Wk,
    const float* __restrict__ Wv, const float* __restrict__ W2, const float* __restrict__ bq,
    f16* __restrict__ Wt, f16* __restrict__ Wqkt, float* __restrict__ bqk, int4* __restrict__ zbuf) {
    __shared__ float Wqs[128][16];
    __shared__ float Wks[128][16];
    int b = blockIdx.x;
    int t = threadIdx.x;
    if (b >= 21) {
        zbuf[(b - 21) * 256 + t] = make_int4(0, 0, 0, 0);
        return;
    }
    if (b < 5) {
        f16* dst = Wt + (size_t)b * 16384;
        if (b == 4) {  // W2: 128k x 64oc
            int oc = t & 63, k0 = (t >> 6) * 32;
            for (int kk = 0; kk < 32; ++kk) {
                int k = k0 + kk;
                dst[oc * 128 + k] = (f16)W2[(size_t)k * 64 + oc];
            }
            return;
        }
        const float* src = (b == 0) ? W1 : Wv + (size_t)(b - 1) * 16384;
        int oc = t >> 1;
        int k0 = (t & 1) * 64;
        for (int kk = 0; kk < 64; ++kk) {
            int k = k0 + kk;
            dst[oc * 128 + k] = (f16)src[k * 128 + oc];
        }
        return;
    }
    // Wqk fold
    int idx = b - 5;
    int l = 1 + (idx >> 3), h = idx & 7;
    const float* WqL = Wq + (size_t)l * 16384;
    const float* WkL = Wk + (size_t)l * 16384;
    for (int i = t; i < 2048; i += 256) {
        int r = i >> 4, c = i & 15;
        Wqs[r][c] = WqL[r * 128 + h * 16 + c];
        Wks[r][c] = WkL[r * 128 + h * 16 + c];
    }
    __syncthreads();
    f16* dst = Wqkt + (size_t)idx * 16384;
    int j = t >> 1, i0 = (t & 1) * 64;
    for (int ii = 0; ii < 64; ++ii) {
        int i = i0 + ii;
        float s = 0.f;
#pragma unroll
        for (int c = 0; c < 16; ++c) s = fmaf(Wqs[i][c], Wks[j][c], s);
        dst[j * 128 + i] = (f16)s;
    }
    if (t < 128) {
        float s = 0.f;
#pragma unroll
        for (int c = 0; c < 16; ++c) s = fmaf(bq[l * 128 + h * 16 + c], Wks[t][c], s);
        bqk[idx * 128 + t] = s;
    }
}

// ---------------- MFMA GEMM ----------------
// mode 0=f32 out, 1=f16+relu, 2=f16 raw, 3=fused final: relu -> @W2t -> +b2 -> log_softmax -> f32 out
struct GJob {
    const void* in; const f16* Wt; const float* bias; const float* rowscale;
    void* out; int ldi; int ldo; int mode; int inF32;
    const f16* Wt2; const float* bias2;
};
struct GJobs { GJob j[8]; };

__global__ __launch_bounds__(256) void gemm_mfma(GJobs jobs, int nrows) {
    const GJob jb = jobs.j[blockIdx.y];
    __shared__ f16 Xl[64 * 128];
    __shared__ f16 Wl[128 * 128];
    const int t = threadIdx.x;
    const int row0 = blockIdx.x * 64;

    half8 zero8;
#pragma unroll
    for (int z = 0; z < 8; ++z) zero8[z] = (f16)0.f;

#pragma unroll
    for (int it = 0; it < 4; ++it) {
        int idx = t + it * 256;
        int r = idx >> 4, c = idx & 15;
        int gr = row0 + r;
        half8 v = zero8;
        if (gr < nrows) {
            if (jb.inF32) {
                const float* fin = (const float*)jb.in + (size_t)gr * jb.ldi + c * 8;
                float4 f0 = ((const float4*)fin)[0];
                float4 f1 = ((const float4*)fin)[1];
                v[0] = (f16)f0.x; v[1] = (f16)f0.y; v[2] = (f16)f0.z; v[3] = (f16)f0.w;
                v[4] = (f16)f1.x; v[5] = (f16)f1.y; v[6] = (f16)f1.z; v[7] = (f16)f1.w;
            } else {
                v = *(const half8*)((const f16*)jb.in + (size_t)gr * jb.ldi + c * 8);
            }
        }
        *(half8*)((char*)Xl + r * 256 + ((c * 16) ^ ((r & 7) << 4))) = v;
    }
#pragma unroll
    for (int it = 0; it < 8; ++it) {
        int idx = t + it * 256;
        int r = idx >> 4, c = idx & 15;
        half8 v = *(const half8*)(jb.Wt + (size_t)r * 128 + c * 8);
        *(half8*)((char*)Wl + r * 256 + ((c * 16) ^ ((r & 7) << 4))) = v;
    }
    __syncthreads();

    const int w = t >> 6, l = t & 63;
    const int lr = l & 15;
    const int lk = l >> 4;

    f32x4 acc[8];
#pragma unroll
    for (int tn = 0; tn < 8; ++tn)
#pragma unroll
        for (int i = 0; i < 4; ++i) acc[tn][i] = 0.f;

    const int arow = w * 16 + lr;
    const int axor = (arow & 7) << 4;
    const int bxor = (lr & 7) << 4;

#pragma unroll
    for (int ks = 0; ks < 4; ++ks) {
        int koff = (ks * 4 + lk) * 16;
        half8 a = *(const half8*)((const char*)Xl + arow * 256 + (koff ^ axor));
#pragma unroll
        for (int tn = 0; tn < 8; ++tn) {
            int oc = tn * 16 + lr;
            half8 b = *(const half8*)((const char*)Wl + oc * 256 + (koff ^ bxor));
            acc[tn] = __builtin_amdgcn_mfma_f32_16x16x32_f16(a, b, acc[tn], 0, 0, 0);
        }
    }

    const int rbase = row0 + w * 16 + (lk << 2);
    float brs[4];
#pragma unroll
    for (int i = 0; i < 4; ++i)
        brs[i] = jb.rowscale ? ((rbase + i < nrows) ? jb.rowscale[rbase + i] : 0.f) : 1.0f;
    float bsv[8];
#pragma unroll
    for (int tn = 0; tn < 8; ++tn) bsv[tn] = jb.bias[tn * 16 + lr];

    if (jb.mode == 0) {
        float* op = (float*)jb.out;
#pragma unroll
        for (int tn = 0; tn < 8; ++tn)
#pragma unroll
            for (int i = 0; i < 4; ++i) {
                int gr = rbase + i;
                if (gr < nrows) op[(size_t)gr * jb.ldo + tn * 16 + lr] = acc[tn][i] + brs[i] * bsv[tn];
            }
    } else if (jb.mode == 1) {
        f16* op = (f16*)jb.out;
#pragma unroll
        for (int tn = 0; tn < 8; ++tn)
#pragma unroll
            for (int i = 0; i < 4; ++i) {
                int gr = rbase + i;
                if (gr < nrows) op[(size_t)gr * jb.ldo + tn * 16 + lr] = (f16)fmaxf(acc[tn][i] + brs[i] * bsv[tn], 0.f);
            }
    } else if (jb.mode == 2) {
        f16* op = (f16*)jb.out;
#pragma unroll
        for (int tn = 0; tn < 8; ++tn)
#pragma unroll
            for (int i = 0; i < 4; ++i) {
                int gr = rbase + i;
                if (gr < nrows) op[(size_t)gr * jb.ldo + tn * 16 + lr] = (f16)(acc[tn][i] + brs[i] * bsv[tn]);
            }
    } else {
        // mode 3: h3 = relu(acc + brs*bsv) -> Xl (swizzled); stage W2t -> Wl; MFMA vs W2t; +b2; log_softmax
        __syncthreads();  // everyone done reading Xl/Wl
#pragma unroll
        for (int tn = 0; tn < 8; ++tn)
#pragma unroll
            for (int i = 0; i < 4; ++i) {
                f16 v = (f16)fmaxf(acc[tn][i] + brs[i] * bsv[tn], 0.f);
                int lrow = w * 16 + (lk << 2) + i;
                int col = tn * 16 + lr;
                int byte = lrow * 256 + ((((col >> 3) * 16) ^ ((lrow & 7) << 4))) + (col & 7) * 2;
                *(f16*)((char*)Xl + byte) = v;
            }
#pragma unroll
        for (int it = 0; it < 4; ++it) {  // W2t: 64 rows x 16 chunks
            int idx = t + it * 256;
            int r = idx >> 4, c = idx & 15;
            half8 v = *(const half8*)(jb.Wt2 + (size_t)r * 128 + c * 8);
            *(half8*)((char*)Wl + r * 256 + ((c * 16) ^ ((r & 7) << 4))) = v;
        }
        __syncthreads();

        f32x4 acc2[4];
#pragma unroll
        for (int tn = 0; tn < 4; ++tn)
#pragma unroll
            for (int i = 0; i < 4; ++i) acc2[tn][i] = 0.f;
#pragma unroll
        for (int ks = 0; ks < 4; ++ks) {
            int koff = (ks * 4 + lk) * 16;
            half8 a = *(const half8*)((const char*)Xl + arow * 256 + (koff ^ axor));
#pragma unroll
            for (int tn = 0; tn < 4; ++tn) {
                int oc = tn * 16 + lr;
                half8 b = *(const half8*)((const char*)Wl + oc * 256 + (koff ^ bxor));
                acc2[tn] = __builtin_amdgcn_mfma_f32_16x16x32_f16(a, b, acc2[tn], 0, 0, 0);
            }
        }
        float bs2[4];
#pragma unroll
        for (int tn = 0; tn < 4; ++tn) bs2[tn] = jb.bias2[tn * 16 + lr];
#pragma unroll
        for (int i = 0; i < 4; ++i) {
            float lg[4];
#pragma unroll
            for (int tn = 0; tn < 4; ++tn) lg[tn] = acc2[tn][i] + bs2[tn];
            float m = fmaxf(fmaxf(lg[0], lg[1]), fmaxf(lg[2], lg[3]));
#pragma unroll
            for (int sft = 1; sft <= 8; sft <<= 1) m = fmaxf(m, __shfl_xor(m, sft));
            float den = 0.f;
#pragma unroll
            for (int tn = 0; tn < 4; ++tn) den += __expf(lg[tn] - m);
#pragma unroll
            for (int sft = 1; sft <= 8; sft <<= 1) den += __shfl_xor(den, sft);
            float lden = logf(den);
            int gr = rbase + i;
            if (gr < nrows) {
                float* op = (float*)jb.out + (size_t)gr * jb.ldo;
#pragma unroll
                for (int tn = 0; tn < 4; ++tn) op[tn * 16 + lr] = lg[tn] - m - lden;
            }
        }
    }
}

// ---------------- layer-1 GCN aggregation, quarter-wave (4 edges/wave) ----------------
__global__ __launch_bounds__(256) void sgather5(
    const int* __restrict__ rowptr, const int* __restrict__ esorted,
    const float* __restrict__ dinv,
    const f16* __restrict__ hsrc /* pack (h0 at offset 0) */, f16* __restrict__ Sh, float* __restrict__ srow) {
    int d = (blockIdx.x * 256 + threadIdx.x) >> 6;
    int lam = threadIdx.x & 63;
    int qe = lam >> 4, le = lam & 15;
    if (d >= NN) return;
    int i0 = rowptr[d], nE = rowptr[d + 1] - i0 + 1;  // + self-loop (j == nE-1); j >= nE: w=0
    float dvd = dinv[d];
    float u[8];
#pragma unroll
    for (int i = 0; i < 8; ++i) u[i] = 0.f;
    float ssum = 0.f;

    auto ldb = [&](int b, float& w, half8& h) {
        int j = b + qe;
        int s = (j < nE - 1) ? esorted[i0 + j] : d;
        w = (j < nE) ? dinv[s] : 0.f;
        h = *(const half8*)(hsrc + (size_t)s * PSTR + le * 8);
    };
    auto cmp = [&](float w, const half8& h) {
#pragma unroll
        for (int i = 0; i < 8; ++i) u[i] = fmaf(w, (float)h[i], u[i]);
        ssum += w;
    };

    float wA, wB; half8 hA, hB;
    ldb(0, wA, hA);
    for (int b = 0; b < nE; b += 8) {
        ldb(b + 4, wB, hB);
        cmp(wA, hA);
        ldb(b + 8, wA, hA);
        cmp(wB, hB);
    }
#pragma unroll
    for (int i = 0; i < 8; ++i) {
        u[i] += __shfl_xor(u[i], 16);
        u[i] += __shfl_xor(u[i], 32);
    }
    ssum += __shfl_xor(ssum, 16);
    ssum += __shfl_xor(ssum, 32);
    if (qe == 0) {
        half8 o;
#pragma unroll
        for (int i = 0; i < 8; ++i) o[i] = (f16)(dvd * u[i]);
        *(half8*)(Sh + (size_t)d * 128 + le * 8) = o;
        if (le == 0) srow[d] = dvd * ssum;
    }
}

// ---------------- node attention (expanded-query, h-only gather), quarter-wave ----------------
// lane: qe = lam>>4 (edge slot), le = lam&15 (channels [8*le,8*le+8), own head g = le>>1)
// score_h = sum_j qk[d,h,j]*h_l[s,j] (k-projection folded into qk dst-side)
template<int L>
__global__ __launch_bounds__(256) void node_attn6(
    const int* __restrict__ rowptr, const int* __restrict__ esorted,
    const float* __restrict__ dinv,
    const f16* __restrict__ qkb, const f16* __restrict__ pack,
    f16* __restrict__ uh) {
    int d = (blockIdx.x * 256 + threadIdx.x) >> 6;
    int lam = threadIdx.x & 63;
    int qe = lam >> 4, le = lam & 15;
    if (d >= NN) return;
    int i0 = rowptr[d], nE = rowptr[d + 1] - i0 + 1;  // self-loop at j == nE-1; j >= nE: w=0
    float dvd = dinv[d];
    half8 qk8[8];
#pragma unroll
    for (int hh = 0; hh < 8; ++hh)
        qk8[hh] = *(const half8*)(qkb + (size_t)d * 1024 + hh * 128 + le * 8);
    const int g = le >> 1;
    const bool b2g = g >= 4, b1g = (g & 2) != 0, b0g = (g & 1) != 0;
    float u[8];
#pragma unroll
    for (int i = 0; i < 8; ++i) u[i] = 0.f;

    auto ldb = [&](int b, float& w, half8 (&h)[L]) {
        int j = b + qe;
        int s = (j < nE - 1) ? esorted[i0 + j] : d;
        w = (j < nE) ? dinv[s] : 0.f;
        const f16* bp = pack + (size_t)s * PSTR + le * 8;
#pragma unroll
        for (int l = 0; l < L; ++l) h[l] = *(const half8*)(bp + l * 128);
    };
    auto cmp = [&](float w, const half8 (&h)[L]) {
        float sel[L];
#pragma unroll
        for (int l = 0; l < L; ++l) {
            float ph[8];
#pragma unroll
            for (int hh = 0; hh < 8; ++hh) {
                const f16x2* ap = (const f16x2*)&qk8[hh];
                const f16x2* hp = (const f16x2*)&h[l];
                float p = 0.f;
#pragma unroll
                for (int i = 0; i < 4; ++i) p = fdot2(ap[i], hp[i], p);
                ph[hh] = p;
            }
#pragma unroll
            for (int st = 1; st <= 8; st <<= 1) {
#pragma unroll
                for (int hh = 0; hh < 8; ++hh) ph[hh] += __shfl_xor(ph[hh], st);
            }
            float a = b2g ? (b1g ? (b0g ? ph[7] : ph[6]) : (b0g ? ph[5] : ph[4]))
                          : (b1g ? (b0g ? ph[3] : ph[2]) : (b0g ? ph[1] : ph[0]));
            sel[l] = a * 0.25f;  // 1/sqrt(16)
        }
        float m = sel[0];
#pragma unroll
        for (int l = 1; l < L; ++l) m = fmaxf(m, sel[l]);
        float den = 0.f;
#pragma unroll
        for (int l = 0; l < L; ++l) { sel[l] = __expf(sel[l] - m); den += sel[l]; }
        float wg = w * __builtin_amdgcn_rcpf(den);
#pragma unroll
        for (int l = 0; l < L; ++l) {
            float a = sel[l] * wg;
#pragma unroll
            for (int i = 0; i < 8; ++i) u[i] = fmaf(a, (float)h[l][i], u[i]);
        }
    };

    float wA, wB; half8 hA[L], hB[L];
    ldb(0, wA, hA);
    for (int b = 0; b < nE; b += 8) {
        ldb(b + 4, wB, hB);
        cmp(wA, hA);
        ldb(b + 8, wA, hA);
        cmp(wB, hB);
    }
#pragma unroll
    for (int i = 0; i < 8; ++i) {
        u[i] += __shfl_xor(u[i], 16);
        u[i] += __shfl_xor(u[i], 32);
    }
    if (qe == 0) {
        half8 o;
#pragma unroll
        for (int i = 0; i < 8; ++i) o[i] = (f16)(dvd * u[i]);
        *(half8*)(uh + (size_t)d * 128 + le * 8) = o;
    }
}

extern "C" void kernel_launch(void* const* d_in, const int* in_sizes, int n_in,
                              void* d_out, int out_size, void* d_ws, size_t ws_size,
                              hipStream_t stream) {
    (void)in_sizes; (void)n_in; (void)out_size; (void)ws_size;
    const float* x  = (const float*)d_in[0];
    const int*   ei = (const int*)d_in[1];
    const float* W1 = (const float*)d_in[2];
    const float* b1 = (const float*)d_in[3];
    const float* Wq = (const float*)d_in[4];
    const float* bq = (const float*)d_in[5];
    const float* Wk = (const float*)d_in[6];
    const float* bk = (const float*)d_in[7];
    const float* Wv = (const float*)d_in[8];
    const float* bv = (const float*)d_in[9];
    const float* W2 = (const float*)d_in[10];
    const float* b2 = (const float*)d_in[11];
    float* out = (float*)d_out;
    (void)bk;  // q·bk is level-constant -> cancels in softmax

    // workspace layout (4-byte words)
    int*    cnt     = (int*)d_ws;                  // 16384
    int*    fill    = cnt + 16384;                 // 16384 (cnt+fill zeroed together)
    int*    rowptr  = fill + 16384;                // 16384 (NN+1)
    int*    esorted = rowptr + 16384;              // 163840
    float*  dinv    = (float*)(esorted + 163840);  // 16384
    float*  srow    = dinv + 16384;                // 16384
    float*  bqk     = srow + 16384;                // 2048 (16 x 128)
    f16*    pack    = (f16*)(bqk + 2048);          // NN x 384 halves [h0 h1 h2]
    f16*    Sh      = pack + (size_t)NN * PSTR;    // N128
    f16*    uh      = Sh + N128;                   // N128
    f16*    qkbuf   = uh + N128;                   // NN x 1024
    f16*    Wt      = qkbuf + (size_t)NN * 1024;   // 5 x 16384 (W1, Wv0..2, W2)
    f16*    Wqkt    = Wt + 5 * 16384;              // 16 x 16384

    prep_fused<<<53, 256, 0, stream>>>(W1, Wq, Wk, Wv, W2, bq, Wt, Wqkt, bqk, (int4*)cnt);
    cnt_count<<<(EE + 255) / 256, 256, 0, stream>>>(ei + EE, cnt);
    scan_rowptr<<<1, 256, 0, stream>>>(cnt, rowptr, dinv);
    scatter_edges<<<(EE + 255) / 256, 256, 0, stream>>>(ei, rowptr, fill, esorted);

    const int gx = (NN + 63) / 64;  // 157
    auto WT = [&](int m) { return Wt + (size_t)m * 16384; };   // 0=W1, 1..3=Wv[l], 4=W2
    auto H  = [&](int lev) { return pack + lev * 128; };       // h-level base (stride PSTR)

    {   // h0 = relu(x @ W1 + b1) -> pack  (reads f32 x directly)
        GJobs jobs{};
        jobs.j[0] = {x, WT(0), b1, nullptr, H(0), HID, PSTR, 1, 1, nullptr, nullptr};
        gemm_mfma<<<dim3(gx, 1), 256, 0, stream>>>(jobs, NN);
    }

    const int nblocks = (NN * 64 + 255) / 256;

    // ---- layer 1 (L=1: softmax over 1 level == identity -> GCN, deferred Wv1) ----
    sgather5<<<nblocks, 256, 0, stream>>>(rowptr, esorted, dinv, pack, Sh, srow);
    {   // h1 = relu(S @ Wv1 + srow*bv1) -> pack
        GJobs jobs{};
        jobs.j[0] = {Sh, WT(1), bv, srow, H(1), HID, PSTR, 1, 0, nullptr, nullptr};
        gemm_mfma<<<dim3(gx, 1), 256, 0, stream>>>(jobs, NN);
    }

    // ---- layers 2,3: qk GEMM (8 head-jobs) -> attention (h-only gather) -> deferred Wv GEMM ----
    for (int l = 1; l < 3; ++l) {
        int L = l + 1;
        GJobs jobs{};
        for (int h = 0; h < 8; ++h) {
            int idx = (l - 1) * 8 + h;
            jobs.j[h] = {H(L - 1), Wqkt + (size_t)idx * 16384, bqk + idx * 128, nullptr,
                         qkbuf + h * 128, PSTR, 1024, 2, 0, nullptr, nullptr};
        }
        gemm_mfma<<<dim3(gx, 8), 256, 0, stream>>>(jobs, NN);

        if (L == 2) node_attn6<2><<<nblocks, 256, 0, stream>>>(rowptr, esorted, dinv, qkbuf, pack, uh);
        if (L == 3) node_attn6<3><<<nblocks, 256, 0, stream>>>(rowptr, esorted, dinv, qkbuf, pack, uh);

        GJobs vjob{};
        if (L == 2) {
            // h2 = relu(u @ Wv2 + srow*bv2) -> pack
            vjob.j[0] = {uh, WT(2), bv + 128, srow, H(2), HID, PSTR, 1, 0, nullptr, nullptr};
        } else {
            // fused: h3 = relu(u @ Wv3 + srow*bv3); out = log_softmax(h3 @ W2 + b2)
            vjob.j[0] = {uh, WT(3), bv + 256, srow, out, HID, 64, 3, 0, WT(4), b2};
        }
        gemm_mfma<<<dim3(gx, 1), 256, 0, stream>>>(vjob, NN);
    }
}

// Round 11
// 178.431 us; speedup vs baseline: 1.3386x; 1.3386x over previous
//
#include <hip/hip_runtime.h>
#include <hip/hip_fp16.h>
#include <math.h>

#define NN 10000
#define EE 160000
#define HID 128
constexpr int N128 = NN * HID;
constexpr int PSTR = 768;  // pack stride in halves: [k0 k1 k2 | h0 h1 h2]
constexpr int HOFF = 384;  // h region offset in pack (halves)

typedef _Float16 f16;
typedef f16 half8 __attribute__((ext_vector_type(8)));
typedef f16 f16x2 __attribute__((ext_vector_type(2)));
typedef float f32x4 __attribute__((ext_vector_type(4)));

#if __has_builtin(__builtin_amdgcn_fdot2)
__device__ inline float fdot2(f16x2 a, f16x2 b, float c) { return __builtin_amdgcn_fdot2(a, b, c, false); }
#else
__device__ inline float fdot2(f16x2 a, f16x2 b, float c) {
    return fmaf((float)a[0], (float)b[0], fmaf((float)a[1], (float)b[1], c));
}
#endif

// ---------------- degree count (by dst) ----------------
__global__ __launch_bounds__(256) void cnt_count(const int* __restrict__ dst, int* __restrict__ cnt) {
    int e = blockIdx.x * 256 + threadIdx.x;
    if (e < EE) atomicAdd(&cnt[dst[e]], 1);
}

// ---------------- single-block exclusive scan -> rowptr, + dinv fused ----------------
__global__ __launch_bounds__(256) void scan_rowptr(const int* __restrict__ cnt, int* __restrict__ rowptr,
                                                   float* __restrict__ dinv) {
    __shared__ int part[256];
    const int PER = (NN + 255) / 256;  // 40
    int t = threadIdx.x;
    int base = t * PER;
    int sum = 0;
    for (int i = 0; i < PER; ++i) {
        int idx = base + i;
        if (idx < NN) {
            int c = cnt[idx];
            sum += c;
            dinv[idx] = rsqrtf((float)c + 1.0f);  // +1 self-loop
        }
    }
    part[t] = sum;
    __syncthreads();
    for (int ofs = 1; ofs < 256; ofs <<= 1) {
        int v = (t >= ofs) ? part[t - ofs] : 0;
        __syncthreads();
        part[t] += v;
        __syncthreads();
    }
    int run = (t > 0) ? part[t - 1] : 0;
    for (int i = 0; i < PER; ++i) {
        int idx = base + i;
        if (idx <= NN) rowptr[idx] = run;
        if (idx < NN) run += cnt[idx];
    }
}

__global__ __launch_bounds__(256) void scatter_edges(const int* __restrict__ ei,
                                                     const int* __restrict__ rowptr,
                                                     int* __restrict__ fill,
                                                     int* __restrict__ esorted) {
    int e = blockIdx.x * 256 + threadIdx.x;
    if (e < EE) {
        int s = ei[e], d = ei[EE + e];
        int pos = rowptr[d] + atomicAdd(&fill[d], 1);
        esorted[pos] = s;
    }
}

// ---------------- fused: weight prep (blocks 0..10) + zero cnt/fill/srow (blocks 11..58) ----------------
__global__ __launch_bounds__(256) void prep_fused(const float* __restrict__ W1, const float* __restrict__ Wq,
                                                  const float* __restrict__ Wk, const float* __restrict__ Wv,
                                                  const float* __restrict__ W2, f16* __restrict__ Wt,
                                                  int4* __restrict__ zbuf) {
    int b = blockIdx.x;  // 0=W1, 1..3=Wq[l], 4..6=Wk[l], 7..9=Wv[l], 10=W2, 11..58 = zero 192KB
    int t = threadIdx.x;
    if (b >= 11) {
        zbuf[(b - 11) * 256 + t] = make_int4(0, 0, 0, 0);
        return;
    }
    f16* dst = Wt + (size_t)b * 16384;
    if (b == 10) {
        int oc = t & 63, k0 = (t >> 6) * 32;
        for (int kk = 0; kk < 32; ++kk) {
            int k = k0 + kk;
            dst[oc * 128 + k] = (f16)W2[(size_t)k * 64 + oc];
        }
        return;
    }
    const float* src = (b == 0) ? W1
                     : (b < 4)  ? Wq + (size_t)(b - 1) * 16384
                     : (b < 7)  ? Wk + (size_t)(b - 4) * 16384
                                : Wv + (size_t)(b - 7) * 16384;
    int oc = t >> 1;
    int k0 = (t & 1) * 64;
    for (int kk = 0; kk < 64; ++kk) {
        int k = k0 + kk;
        dst[oc * 128 + k] = (f16)src[k * 128 + oc];
    }
}

// ---------------- MFMA GEMM ----------------
// mode 0=f32 out, 1=f16+relu, 2=f16 raw, 3=fused final: relu -> @W2t -> +b2 -> log_softmax -> f32 out
// in2 (optional, f16 path only): X-stage loads in[r]+in2[r] (two-half accumulator merge)
struct GJob {
    const void* in; const f16* Wt; const float* bias; const float* rowscale;
    void* out; int ldi; int ldo; int mode; int inF32;
    const f16* Wt2; const float* bias2; const f16* in2;
};
struct GJobs { GJob j[7]; };

__global__ __launch_bounds__(256) void gemm_mfma(GJobs jobs, int nrows) {
    const GJob jb = jobs.j[blockIdx.y];
    __shared__ f16 Xl[64 * 128];
    __shared__ f16 Wl[128 * 128];
    const int t = threadIdx.x;
    const int row0 = blockIdx.x * 64;

    half8 zero8;
#pragma unroll
    for (int z = 0; z < 8; ++z) zero8[z] = (f16)0.f;

#pragma unroll
    for (int it = 0; it < 4; ++it) {
        int idx = t + it * 256;
        int r = idx >> 4, c = idx & 15;
        int gr = row0 + r;
        half8 v = zero8;
        if (gr < nrows) {
            if (jb.inF32) {
                const float* fin = (const float*)jb.in + (size_t)gr * jb.ldi + c * 8;
                float4 f0 = ((const float4*)fin)[0];
                float4 f1 = ((const float4*)fin)[1];
                v[0] = (f16)f0.x; v[1] = (f16)f0.y; v[2] = (f16)f0.z; v[3] = (f16)f0.w;
                v[4] = (f16)f1.x; v[5] = (f16)f1.y; v[6] = (f16)f1.z; v[7] = (f16)f1.w;
            } else {
                v = *(const half8*)((const f16*)jb.in + (size_t)gr * jb.ldi + c * 8);
                if (jb.in2) {
                    half8 v2 = *(const half8*)(jb.in2 + (size_t)gr * jb.ldi + c * 8);
                    v = v + v2;
                }
            }
        }
        *(half8*)((char*)Xl + r * 256 + ((c * 16) ^ ((r & 7) << 4))) = v;
    }
#pragma unroll
    for (int it = 0; it < 8; ++it) {
        int idx = t + it * 256;
        int r = idx >> 4, c = idx & 15;
        half8 v = *(const half8*)(jb.Wt + (size_t)r * 128 + c * 8);
        *(half8*)((char*)Wl + r * 256 + ((c * 16) ^ ((r & 7) << 4))) = v;
    }
    __syncthreads();

    const int w = t >> 6, l = t & 63;
    const int lr = l & 15;
    const int lk = l >> 4;

    f32x4 acc[8];
#pragma unroll
    for (int tn = 0; tn < 8; ++tn)
#pragma unroll
        for (int i = 0; i < 4; ++i) acc[tn][i] = 0.f;

    const int arow = w * 16 + lr;
    const int axor = (arow & 7) << 4;
    const int bxor = (lr & 7) << 4;

#pragma unroll
    for (int ks = 0; ks < 4; ++ks) {
        int koff = (ks * 4 + lk) * 16;
        half8 a = *(const half8*)((const char*)Xl + arow * 256 + (koff ^ axor));
#pragma unroll
        for (int tn = 0; tn < 8; ++tn) {
            int oc = tn * 16 + lr;
            half8 b = *(const half8*)((const char*)Wl + oc * 256 + (koff ^ bxor));
            acc[tn] = __builtin_amdgcn_mfma_f32_16x16x32_f16(a, b, acc[tn], 0, 0, 0);
        }
    }

    const int rbase = row0 + w * 16 + (lk << 2);
    float brs[4];
#pragma unroll
    for (int i = 0; i < 4; ++i)
        brs[i] = jb.rowscale ? ((rbase + i < nrows) ? jb.rowscale[rbase + i] : 0.f) : 1.0f;
    float bsv[8];
#pragma unroll
    for (int tn = 0; tn < 8; ++tn) bsv[tn] = jb.bias[tn * 16 + lr];

    if (jb.mode == 0) {
        float* op = (float*)jb.out;
#pragma unroll
        for (int tn = 0; tn < 8; ++tn)
#pragma unroll
            for (int i = 0; i < 4; ++i) {
                int gr = rbase + i;
                if (gr < nrows) op[(size_t)gr * jb.ldo + tn * 16 + lr] = acc[tn][i] + brs[i] * bsv[tn];
            }
    } else if (jb.mode == 1) {
        f16* op = (f16*)jb.out;
#pragma unroll
        for (int tn = 0; tn < 8; ++tn)
#pragma unroll
            for (int i = 0; i < 4; ++i) {
                int gr = rbase + i;
                if (gr < nrows) op[(size_t)gr * jb.ldo + tn * 16 + lr] = (f16)fmaxf(acc[tn][i] + brs[i] * bsv[tn], 0.f);
            }
    } else if (jb.mode == 2) {
        f16* op = (f16*)jb.out;
#pragma unroll
        for (int tn = 0; tn < 8; ++tn)
#pragma unroll
            for (int i = 0; i < 4; ++i) {
                int gr = rbase + i;
                if (gr < nrows) op[(size_t)gr * jb.ldo + tn * 16 + lr] = (f16)(acc[tn][i] + brs[i] * bsv[tn]);
            }
    } else {
        // mode 3: h3 = relu(acc + brs*bsv) -> Xl (swizzled); stage W2t -> Wl; MFMA vs W2t; +b2; log_softmax
        __syncthreads();  // everyone done reading Xl/Wl
#pragma unroll
        for (int tn = 0; tn < 8; ++tn)
#pragma unroll
            for (int i = 0; i < 4; ++i) {
                f16 v = (f16)fmaxf(acc[tn][i] + brs[i] * bsv[tn], 0.f);
                int lrow = w * 16 + (lk << 2) + i;
                int col = tn * 16 + lr;
                int byte = lrow * 256 + ((((col >> 3) * 16) ^ ((lrow & 7) << 4))) + (col & 7) * 2;
                *(f16*)((char*)Xl + byte) = v;
            }
#pragma unroll
        for (int it = 0; it < 4; ++it) {  // W2t: 64 rows x 16 chunks
            int idx = t + it * 256;
            int r = idx >> 4, c = idx & 15;
            half8 v = *(const half8*)(jb.Wt2 + (size_t)r * 128 + c * 8);
            *(half8*)((char*)Wl + r * 256 + ((c * 16) ^ ((r & 7) << 4))) = v;
        }
        __syncthreads();

        f32x4 acc2[4];
#pragma unroll
        for (int tn = 0; tn < 4; ++tn)
#pragma unroll
            for (int i = 0; i < 4; ++i) acc2[tn][i] = 0.f;
#pragma unroll
        for (int ks = 0; ks < 4; ++ks) {
            int koff = (ks * 4 + lk) * 16;
            half8 a = *(const half8*)((const char*)Xl + arow * 256 + (koff ^ axor));
#pragma unroll
            for (int tn = 0; tn < 4; ++tn) {
                int oc = tn * 16 + lr;
                half8 b = *(const half8*)((const char*)Wl + oc * 256 + (koff ^ bxor));
                acc2[tn] = __builtin_amdgcn_mfma_f32_16x16x32_f16(a, b, acc2[tn], 0, 0, 0);
            }
        }
        float bs2[4];
#pragma unroll
        for (int tn = 0; tn < 4; ++tn) bs2[tn] = jb.bias2[tn * 16 + lr];
#pragma unroll
        for (int i = 0; i < 4; ++i) {
            float lg[4];
#pragma unroll
            for (int tn = 0; tn < 4; ++tn) lg[tn] = acc2[tn][i] + bs2[tn];
            float m = fmaxf(fmaxf(lg[0], lg[1]), fmaxf(lg[2], lg[3]));
#pragma unroll
            for (int sft = 1; sft <= 8; sft <<= 1) m = fmaxf(m, __shfl_xor(m, sft));
            float den = 0.f;
#pragma unroll
            for (int tn = 0; tn < 4; ++tn) den += __expf(lg[tn] - m);
#pragma unroll
            for (int sft = 1; sft <= 8; sft <<= 1) den += __shfl_xor(den, sft);
            float lden = logf(den);
            int gr = rbase + i;
            if (gr < nrows) {
                float* op = (float*)jb.out + (size_t)gr * jb.ldo;
#pragma unroll
                for (int tn = 0; tn < 4; ++tn) op[tn * 16 + lr] = lg[tn] - m - lden;
            }
        }
    }
}

// ---------------- layer-1 GCN aggregation, quarter-wave, 2 half-waves per node ----------------
__global__ __launch_bounds__(256) void sgather6(
    const int* __restrict__ rowptr, const int* __restrict__ esorted,
    const float* __restrict__ dinv,
    const f16* __restrict__ hsrc /* pack + HOFF */, f16* __restrict__ Sh0, f16* __restrict__ Sh1,
    float* __restrict__ srow) {
    int wid = (blockIdx.x * 256 + threadIdx.x) >> 6;
    int lam = threadIdx.x & 63;
    int qe = lam >> 4, le = lam & 15;
    if (wid >= 2 * NN) return;
    int d = wid >> 1, half = wid & 1;
    int i0 = rowptr[d], nE = rowptr[d + 1] - i0 + 1;  // + self-loop at j == nE-1
    int mid = (nE + 1) >> 1;
    int lo = half ? mid : 0, hi = half ? nE : mid;
    float dvd = dinv[d];
    float u[8];
#pragma unroll
    for (int i = 0; i < 8; ++i) u[i] = 0.f;
    float ssum = 0.f;

    auto ldb = [&](int b, float& w, half8& h) {
        int j = b + qe;
        int s = (j < nE - 1) ? esorted[i0 + j] : d;
        w = (j < hi) ? dinv[s] : 0.f;
        h = *(const half8*)(hsrc + (size_t)s * PSTR + le * 8);
    };
    auto cmp = [&](float w, const half8& h) {
#pragma unroll
        for (int i = 0; i < 8; ++i) u[i] = fmaf(w, (float)h[i], u[i]);
        ssum += w;
    };

    float wA, wB; half8 hA, hB;
    ldb(lo, wA, hA);
    for (int b = lo; b < hi; b += 8) {
        ldb(b + 4, wB, hB);
        cmp(wA, hA);
        ldb(b + 8, wA, hA);
        cmp(wB, hB);
    }
#pragma unroll
    for (int i = 0; i < 8; ++i) {
        u[i] += __shfl_xor(u[i], 16);
        u[i] += __shfl_xor(u[i], 32);
    }
    ssum += __shfl_xor(ssum, 16);
    ssum += __shfl_xor(ssum, 32);
    if (qe == 0) {
        f16* Sh = half ? Sh1 : Sh0;
        half8 o;
#pragma unroll
        for (int i = 0; i < 8; ++i) o[i] = (f16)(dvd * u[i]);
        *(half8*)(Sh + (size_t)d * 128 + le * 8) = o;
        if (le == 0) atomicAdd(&srow[d], dvd * ssum);
    }
}

// ---------------- node attention (deferred V), quarter-wave, 2 half-waves per node ----------------
// lane: qe = lam>>4 (edge slot), le = lam&15 (channels [8*le,8*le+8), head = le>>1)
template<int L>
__global__ __launch_bounds__(256) void node_attn7(
    const int* __restrict__ rowptr, const int* __restrict__ esorted,
    const float* __restrict__ dinv,
    const f16* __restrict__ qh, const f16* __restrict__ pack,
    f16* __restrict__ uh0, f16* __restrict__ uh1) {
    int wid = (blockIdx.x * 256 + threadIdx.x) >> 6;
    int lam = threadIdx.x & 63;
    int qe = lam >> 4, le = lam & 15;
    if (wid >= 2 * NN) return;
    int d = wid >> 1, half = wid & 1;
    int i0 = rowptr[d], nE = rowptr[d + 1] - i0 + 1;  // self-loop at j == nE-1
    int mid = (nE + 1) >> 1;
    int lo = half ? mid : 0, hi = half ? nE : mid;
    float dvd = dinv[d];
    half8 q8 = *(const half8*)(qh + (size_t)d * 128 + le * 8);
    const f16x2* qp = (const f16x2*)&q8;
    float u[8];
#pragma unroll
    for (int i = 0; i < 8; ++i) u[i] = 0.f;

    auto ldb = [&](int b, float& w, half8 (&k)[L], half8 (&h)[L]) {
        int j = b + qe;
        int s = (j < nE - 1) ? esorted[i0 + j] : d;
        w = (j < hi) ? dinv[s] : 0.f;
        const f16* bp = pack + (size_t)s * PSTR + le * 8;
#pragma unroll
        for (int l = 0; l < L; ++l) {
            k[l] = *(const half8*)(bp + l * 128);
            h[l] = *(const half8*)(bp + HOFF + l * 128);
        }
    };
    auto cmp = [&](float w, const half8 (&k)[L], const half8 (&h)[L]) {
        float sc[L];
#pragma unroll
        for (int l = 0; l < L; ++l) {
            const f16x2* kp = (const f16x2*)&k[l];
            float p = 0.f;
#pragma unroll
            for (int i = 0; i < 4; ++i) p = fdot2(qp[i], kp[i], p);
            p += __shfl_xor(p, 1);  // partner lane holds the head's other 8 channels
            sc[l] = p * 0.25f;      // 1/sqrt(16)
        }
        float m = sc[0];
#pragma unroll
        for (int l = 1; l < L; ++l) m = fmaxf(m, sc[l]);
        float den = 0.f;
#pragma unroll
        for (int l = 0; l < L; ++l) { sc[l] = __expf(sc[l] - m); den += sc[l]; }
        float wg = w * __builtin_amdgcn_rcpf(den);
#pragma unroll
        for (int l = 0; l < L; ++l) {
            float a = sc[l] * wg;
#pragma unroll
            for (int i = 0; i < 8; ++i) u[i] = fmaf(a, (float)h[l][i], u[i]);
        }
    };

    float wA, wB; half8 kA[L], hA[L], kB[L], hB[L];
    ldb(lo, wA, kA, hA);
    for (int b = lo; b < hi; b += 8) {
        ldb(b + 4, wB, kB, hB);
        cmp(wA, kA, hA);
        ldb(b + 8, wA, kA, hA);
        cmp(wB, kB, hB);
    }
#pragma unroll
    for (int i = 0; i < 8; ++i) {
        u[i] += __shfl_xor(u[i], 16);
        u[i] += __shfl_xor(u[i], 32);
    }
    if (qe == 0) {
        f16* uh = half ? uh1 : uh0;
        half8 o;
#pragma unroll
        for (int i = 0; i < 8; ++i) o[i] = (f16)(dvd * u[i]);
        *(half8*)(uh + (size_t)d * 128 + le * 8) = o;
    }
}

extern "C" void kernel_launch(void* const* d_in, const int* in_sizes, int n_in,
                              void* d_out, int out_size, void* d_ws, size_t ws_size,
                              hipStream_t stream) {
    (void)in_sizes; (void)n_in; (void)out_size; (void)ws_size;
    const float* x  = (const float*)d_in[0];
    const int*   ei = (const int*)d_in[1];
    const float* W1 = (const float*)d_in[2];
    const float* b1 = (const float*)d_in[3];
    const float* Wq = (const float*)d_in[4];
    const float* bq = (const float*)d_in[5];
    const float* Wk = (const float*)d_in[6];
    const float* bk = (const float*)d_in[7];
    const float* Wv = (const float*)d_in[8];
    const float* bv = (const float*)d_in[9];
    const float* W2 = (const float*)d_in[10];
    const float* b2 = (const float*)d_in[11];
    float* out = (float*)d_out;

    // workspace layout (4-byte words); cnt+fill+srow contiguous -> zeroed by prep_fused
    int*    cnt     = (int*)d_ws;                  // 16384
    int*    fill    = cnt + 16384;                 // 16384
    float*  srow    = (float*)(fill + 16384);      // 16384 (zeroed; atomicAdd target)
    int*    rowptr  = (int*)(srow + 16384);        // 16384 (NN+1)
    int*    esorted = rowptr + 16384;              // 163840
    float*  dinv    = (float*)(esorted + 163840);  // 16384
    f16*    pack    = (f16*)(dinv + 16384);        // NN x 768 halves
    f16*    Sh0     = pack + (size_t)NN * PSTR;    // N128
    f16*    Sh1     = Sh0 + N128;                  // N128
    f16*    qh      = Sh1 + N128;                  // N128
    f16*    uh0     = qh + N128;                   // N128
    f16*    uh1     = uh0 + N128;                  // N128
    f16*    Wt      = uh1 + N128;                  // 11 x 16384

    prep_fused<<<59, 256, 0, stream>>>(W1, Wq, Wk, Wv, W2, Wt, (int4*)cnt);  // 48 zero blocks = 192KB
    cnt_count<<<(EE + 255) / 256, 256, 0, stream>>>(ei + EE, cnt);
    scan_rowptr<<<1, 256, 0, stream>>>(cnt, rowptr, dinv);
    scatter_edges<<<(EE + 255) / 256, 256, 0, stream>>>(ei, rowptr, fill, esorted);

    const int gx = (NN + 63) / 64;  // 157
    auto WT = [&](int m) { return Wt + (size_t)m * 16384; };  // 0=W1,1..3=Wq,4..6=Wk,7..9=Wv,10=W2
    auto H  = [&](int lev) { return pack + HOFF + lev * 128; };  // h-level base (stride PSTR)
    auto K  = [&](int lev) { return pack + lev * 128; };         // k-level base (stride PSTR)

    {   // h0 = relu(x @ W1 + b1) -> pack  (reads f32 x directly)
        GJobs jobs{};
        jobs.j[0] = {x, WT(0), b1, nullptr, H(0), HID, PSTR, 1, 1, nullptr, nullptr, nullptr};
        gemm_mfma<<<dim3(gx, 1), 256, 0, stream>>>(jobs, NN);
    }

    const int nblocks = (2 * NN * 64 + 255) / 256;  // 5000 (2 half-waves per node)

    // ---- layer 1 (L=1: softmax over 1 level == identity -> GCN, deferred Wv1) ----
    sgather6<<<nblocks, 256, 0, stream>>>(rowptr, esorted, dinv, pack + HOFF, Sh0, Sh1, srow);
    {   // h1 = relu((S0+S1) @ Wv1 + srow*bv1) -> pack
        GJobs jobs{};
        jobs.j[0] = {Sh0, WT(7), bv, srow, H(1), HID, PSTR, 1, 0, nullptr, nullptr, Sh1};
        gemm_mfma<<<dim3(gx, 1), 256, 0, stream>>>(jobs, NN);
    }

    // ---- layers 2,3: q/k GEMMs -> attention (aggregate raw h) -> deferred Wv GEMM ----
    for (int l = 1; l < 3; ++l) {
        int L = l + 1;
        GJobs jobs{};
        jobs.j[0] = {H(L - 1), WT(1 + l), bq + l * HID, nullptr, qh, PSTR, HID, 2, 0, nullptr, nullptr, nullptr};
        for (int lev = 0; lev < L; ++lev)
            jobs.j[1 + lev] = {H(lev), WT(4 + l), bk + l * HID, nullptr, K(lev), PSTR, PSTR, 2, 0, nullptr, nullptr, nullptr};
        gemm_mfma<<<dim3(gx, 1 + L), 256, 0, stream>>>(jobs, NN);

        if (L == 2) node_attn7<2><<<nblocks, 256, 0, stream>>>(rowptr, esorted, dinv, qh, pack, uh0, uh1);
        if (L == 3) node_attn7<3><<<nblocks, 256, 0, stream>>>(rowptr, esorted, dinv, qh, pack, uh0, uh1);

        GJobs vjob{};
        if (L == 2) {
            // h2 = relu((u0+u1) @ Wv2 + srow*bv2) -> pack
            vjob.j[0] = {uh0, WT(7 + l), bv + l * HID, srow, H(2), HID, PSTR, 1, 0, nullptr, nullptr, uh1};
        } else {
            // fused: h3 = relu((u0+u1) @ Wv3 + srow*bv3); out = log_softmax(h3 @ W2 + b2)
            vjob.j[0] = {uh0, WT(7 + l), bv + l * HID, srow, out, HID, 64, 3, 0, WT(10), b2, uh1};
        }
        gemm_mfma<<<dim3(gx, 1), 256, 0, stream>>>(vjob, NN);
    }
}